// Round 7
// baseline (766.375 us; speedup 1.0000x reference)
//
#include <hip/hip_runtime.h>

// RegressorHybrid: per-edge 2x MLP (128->64->64->32->1, lrelu 0.01), E=2M, H=64.
// Round 7: dual-tile MFMA (32 edges/wave-iter) — each LDS A-fragment read once,
// used by two MFMAs (tile a, tile b): halves per-edge LDS traffic + doubles
// in-wave ILP (R6 was latency-bound at 8 waves/CU, LDS A-reads biggest term).
// Keeps R6's warm-pass gather law: each missing b128 lane-request = own 64B
// fill; warm instr (dword, lane-private line) 3 iters ahead -> consume hits.
// Preps fused into one kernel (blocks 0-67 e-frags, 68-135 w-frags, rest f16
// node conversion). __launch_bounds__(256,2): LDS 57KB caps 2 blocks/CU anyway.
// MFMA layouts: A[m=lane&15][k=(lane>>4)*8+j], B[k=(lane>>4)*8+j][n=lane&15],
//               C/D[row=4*(lane>>4)+reg][col=lane&15].

typedef _Float16 half8  __attribute__((ext_vector_type(8)));
typedef _Float16 half4v __attribute__((ext_vector_type(4)));
typedef float    float4v __attribute__((ext_vector_type(4)));

#define LDS_PER_MLP 28672          // w1f 16384 + w2f 8192 + w3f 4096
#define LDS_TOTAL   57344
#define REST_PER_MLP 12288         // w4f 2048 + b1f 4096 + b2f 4096 + b3f 2048
#define W1F 0
#define W2F 16384
#define W3F 24576
#define RW4F 0
#define RB1F 2048
#define RB2F 6144
#define RB3F 10240
#define WS_REST_OFF 57344
#define WS_X16_OFF  81920

__device__ __forceinline__ float lrelu(float x) { return fmaxf(x, 0.01f * x); }

__device__ __forceinline__ int uperm(int k) {
    return 16 * (2 * ((k >> 2) & 1) + ((k >> 5) & 1)) + 4 * ((k >> 3) & 3) + (k & 3);
}

// ---- fused prep: blocks 0..67 e-frags, 68..135 w-frags, rest node f16 ----
__device__ __forceinline__ void pack_frags(int idx,
                           const float* __restrict__ w1, const float* __restrict__ b1,
                           const float* __restrict__ w2, const float* __restrict__ b2,
                           const float* __restrict__ w3, const float* __restrict__ b3,
                           const float* __restrict__ w4,
                           unsigned char* __restrict__ dstL,
                           unsigned char* __restrict__ dstR)
{
    if (idx < 8192) {                      // w1f: [16 frags][64 lanes][8 f16]
        int L = (idx >> 3) & 63, j = idx & 7, f = idx >> 9;
        int q = L >> 4, mm = L & 15, t = f >> 2, s = f & 3;
        int k = 32 * s + 8 * q + j;
        ((_Float16*)(dstL + W1F))[idx] = (_Float16)w1[k * 64 + 16 * t + mm];
        return;
    }
    idx -= 8192;
    if (idx < 4096) {                      // w2f: [8][64][8]
        int L = (idx >> 3) & 63, j = idx & 7, f = idx >> 9;
        int q = L >> 4, mm = L & 15, t = f >> 1, s = f & 1;
        int u = uperm(32 * s + 8 * q + j);
        ((_Float16*)(dstL + W2F))[idx] = (_Float16)w2[u * 64 + 16 * t + mm];
        return;
    }
    idx -= 4096;
    if (idx < 2048) {                      // w3f: [4][64][8]
        int L = (idx >> 3) & 63, j = idx & 7, f = idx >> 9;
        int q = L >> 4, mm = L & 15, t = f >> 1, s = f & 1;
        int u = uperm(32 * s + 8 * q + j);
        ((_Float16*)(dstL + W3F))[idx] = (_Float16)w3[u * 32 + 16 * t + mm];
        return;
    }
    idx -= 2048;
    if (idx < 512) {                       // w4f
        int L = idx >> 3, j = idx & 7;
        int q = L >> 4, t = j >> 2, r = j & 3;
        ((float*)(dstR + RW4F))[idx] = w4[16 * t + 4 * q + r];
        return;
    }
    idx -= 512;
    if (idx < 1024) {                      // b1f: [4 t][64 lanes][4 f32]
        int t = idx >> 8, L = (idx >> 2) & 63, r = idx & 3, q = L >> 4;
        ((float*)(dstR + RB1F))[idx] = b1[16 * t + 4 * q + r];
        return;
    }
    idx -= 1024;
    if (idx < 1024) {                      // b2f
        int t = idx >> 8, L = (idx >> 2) & 63, r = idx & 3, q = L >> 4;
        ((float*)(dstR + RB2F))[idx] = b2[16 * t + 4 * q + r];
        return;
    }
    idx -= 1024;
    if (idx < 512) {                       // b3f
        int t = idx >> 8, L = (idx >> 2) & 63, r = idx & 3, q = L >> 4;
        ((float*)(dstR + RB3F))[idx] = b3[16 * t + 4 * q + r];
        return;
    }
}

__global__ __launch_bounds__(256)
void prep_all(const float* __restrict__ ew1, const float* __restrict__ eb1,
              const float* __restrict__ ew2, const float* __restrict__ eb2,
              const float* __restrict__ ew3, const float* __restrict__ eb3,
              const float* __restrict__ ew4,
              const float* __restrict__ ww1, const float* __restrict__ wb1,
              const float* __restrict__ ww2, const float* __restrict__ wb2,
              const float* __restrict__ ww3, const float* __restrict__ wb3,
              const float* __restrict__ ww4,
              const float* __restrict__ xs, const float* __restrict__ xd,
              _Float16* __restrict__ os, _Float16* __restrict__ od, int n4,
              unsigned char* __restrict__ ws)
{
    int b = blockIdx.x;
    if (b < 68) {
        pack_frags(b * 256 + threadIdx.x, ew1, eb1, ew2, eb2, ew3, eb3, ew4,
                   ws, ws + WS_REST_OFF);
        return;
    }
    if (b < 136) {
        pack_frags((b - 68) * 256 + threadIdx.x, ww1, wb1, ww2, wb2, ww3, wb3, ww4,
                   ws + LDS_PER_MLP, ws + WS_REST_OFF + REST_PER_MLP);
        return;
    }
    int stride = (gridDim.x - 136) * 256;
    for (int i = (b - 136) * 256 + threadIdx.x; i < n4; i += stride) {
        float4v a = ((const float4v*)xs)[i];
        float4v c = ((const float4v*)xd)[i];
        half4v ha, hb;
#pragma unroll
        for (int j = 0; j < 4; ++j) { ha[j] = (_Float16)a[j]; hb[j] = (_Float16)c[j]; }
        ((half4v*)os)[i] = ha;
        ((half4v*)od)[i] = hb;
    }
}

__device__ __forceinline__ half8 repack2(float4v lo, float4v hi) {
    half8 r;
#pragma unroll
    for (int j = 0; j < 4; ++j) r[j] = (_Float16)lrelu(lo[j]);
#pragma unroll
    for (int j = 0; j < 4; ++j) r[4 + j] = (_Float16)lrelu(hi[j]);
    return r;
}

// consume gather (hits warmed lines): lane (q,n) loads chunk q of edge n's lines
__device__ __forceinline__ void gather_tile(const _Float16* __restrict__ xs,
                                            const _Float16* __restrict__ xd,
                                            const int* __restrict__ eidx,
                                            int nE, int tile, int q, int n, int4* G)
{
    int e = tile * 16 + n;
    int ec = e < nE ? e : nE - 1;
    int si = eidx[ec];
    int di = eidx[nE + ec];
    const char* rs = (const char*)(xs + (size_t)si * 64);
    const char* rd = (const char*)(xd + (size_t)di * 64);
    G[0] = *(const int4*)(rs + 16 * q);
    G[1] = *(const int4*)(rs + 64 + 16 * q);
    G[2] = *(const int4*)(rd + 16 * q);
    G[3] = *(const int4*)(rd + 64 + 16 * q);
}

// warm: lane (c=q, n) touches line (edge n, combo c) once -> 64 distinct lines
// per instruction, one 64B fill each. Dword is enough to fill the line.
__device__ __forceinline__ int warm_tile(const _Float16* __restrict__ xs,
                                         const _Float16* __restrict__ xd,
                                         const int* __restrict__ eidx,
                                         int nE, int tile, int c, int n)
{
    int e = tile * 16 + n;
    int ec = e < nE ? e : nE - 1;
    int idx = (c & 2) ? eidx[nE + ec] : eidx[ec];
    const char* base = (const char*)(((c & 2) ? xd : xs) + (size_t)idx * 64);
    return *(const int*)(base + (c & 1) * 64);
}

__global__ __launch_bounds__(256, 2)
void edge_mlp_mfma(const unsigned char* __restrict__ ws,
                   const _Float16* __restrict__ xs, const _Float16* __restrict__ xd,
                   const int* __restrict__ eidx,
                   const float* __restrict__ eb4p, const float* __restrict__ wb4p,
                   float* __restrict__ out, int nE, int nt32)
{
    __shared__ unsigned char lds[LDS_TOTAL];
    {
        const uint4* s = (const uint4*)ws;
        uint4* d = (uint4*)lds;
        for (int i = threadIdx.x; i < LDS_TOTAL / 16; i += 256) d[i] = s[i];
    }
    __syncthreads();

    const int lane = threadIdx.x & 63;
    const int q = lane >> 4, n = lane & 15;
    const int wid = (blockIdx.x << 2) | (threadIdx.x >> 6);
    const int nwaves = gridDim.x << 2;
    const float b4s0 = eb4p[0], b4s1 = wb4p[0];
    const int ntiles = nt32 * 2;   // 16-edge tiles (nE=2M -> even split)

    // hoisted bias / w4 fragments (loop-invariant, in VGPRs)
    float4v b1v[2][4], b2v[2][4], b3v[2][2], w4v[2][2];
#pragma unroll
    for (int m = 0; m < 2; ++m) {
        const unsigned char* rb = ws + WS_REST_OFF + m * REST_PER_MLP;
#pragma unroll
        for (int t = 0; t < 4; ++t) b1v[m][t] = *(const float4v*)(rb + RB1F + (t * 64 + lane) * 16);
#pragma unroll
        for (int t = 0; t < 4; ++t) b2v[m][t] = *(const float4v*)(rb + RB2F + (t * 64 + lane) * 16);
#pragma unroll
        for (int t = 0; t < 2; ++t) b3v[m][t] = *(const float4v*)(rb + RB3F + (t * 64 + lane) * 16);
        w4v[m][0] = *(const float4v*)(rb + RW4F + lane * 32);
        w4v[m][1] = *(const float4v*)(rb + RW4F + lane * 32 + 16);
    }

    int4 GA[4], GB[4], GAn[4], GBn[4];
    int Wa0 = 0, Wb0 = 0, Wa1 = 0, Wb1 = 0, Wa2 = 0, Wb2 = 0, junk = 0;

    int it = wid;
    if (it < nt32) {
        int i1 = it + nwaves;     if (i1 >= nt32) i1 = nt32 - 1;
        int i2 = it + 2 * nwaves; if (i2 >= nt32) i2 = nt32 - 1;
        Wa0 = warm_tile(xs, xd, eidx, nE, 2 * it, q, n);
        Wb0 = warm_tile(xs, xd, eidx, nE, 2 * it + 1, q, n);
        Wa1 = warm_tile(xs, xd, eidx, nE, 2 * i1, q, n);
        Wb1 = warm_tile(xs, xd, eidx, nE, 2 * i1 + 1, q, n);
        Wa2 = warm_tile(xs, xd, eidx, nE, 2 * i2, q, n);
        Wb2 = warm_tile(xs, xd, eidx, nE, 2 * i2 + 1, q, n);
        gather_tile(xs, xd, eidx, nE, 2 * it, q, n, GA);
        gather_tile(xs, xd, eidx, nE, 2 * it + 1, q, n, GB);
    }

#pragma unroll 1
    for (; it < nt32; it += nwaves) {
        const int ta = 2 * it, tb = 2 * it + 1;
        half8 B1a[4], B1b[4];
#pragma unroll
        for (int s = 0; s < 4; ++s) {
            B1a[s] = __builtin_bit_cast(half8, GA[s]);
            B1b[s] = __builtin_bit_cast(half8, GB[s]);
        }

        // prefetch next iteration's consume gathers (hit warmed lines)
        int in1 = it + nwaves;
        if (in1 < nt32) {
            gather_tile(xs, xd, eidx, nE, 2 * in1, q, n, GAn);
            gather_tile(xs, xd, eidx, nE, 2 * in1 + 1, q, n, GBn);
        }

        // fold oldest warm (2 iters old), rotate, issue warm for iter+3
        junk ^= Wa0 ^ Wb0;
        Wa0 = Wa1; Wb0 = Wb1; Wa1 = Wa2; Wb1 = Wb2;
        {
            int iw = it + 3 * nwaves;
            if (iw >= nt32) iw = nt32 - 1;
            Wa2 = warm_tile(xs, xd, eidx, nE, 2 * iw, q, n);
            Wb2 = warm_tile(xs, xd, eidx, nE, 2 * iw + 1, q, n);
        }

        float resA0, resA1, resB0, resB1;
#pragma unroll
        for (int m = 0; m < 2; ++m) {
            const unsigned char* mb = lds + m * LDS_PER_MLP;
            // ---- layer 1: 128 -> 64, A read once, two MFMAs ----
            float4v accA[4], accB[4];
#pragma unroll
            for (int t = 0; t < 4; ++t) {
                accA[t] = b1v[m][t];
                accB[t] = b1v[m][t];
#pragma unroll
                for (int s = 0; s < 4; ++s) {
                    half8 A = *(const half8*)(mb + W1F + ((t * 4 + s) * 64 + lane) * 16);
                    accA[t] = __builtin_amdgcn_mfma_f32_16x16x32_f16(A, B1a[s], accA[t], 0, 0, 0);
                    accB[t] = __builtin_amdgcn_mfma_f32_16x16x32_f16(A, B1b[s], accB[t], 0, 0, 0);
                }
            }
            // ---- layer 2: 64 -> 64 ----
            half8 B2a[2] = { repack2(accA[0], accA[2]), repack2(accA[1], accA[3]) };
            half8 B2b[2] = { repack2(accB[0], accB[2]), repack2(accB[1], accB[3]) };
            float4v ac2A[4], ac2B[4];
#pragma unroll
            for (int t = 0; t < 4; ++t) {
                ac2A[t] = b2v[m][t];
                ac2B[t] = b2v[m][t];
#pragma unroll
                for (int s = 0; s < 2; ++s) {
                    half8 A = *(const half8*)(mb + W2F + ((t * 2 + s) * 64 + lane) * 16);
                    ac2A[t] = __builtin_amdgcn_mfma_f32_16x16x32_f16(A, B2a[s], ac2A[t], 0, 0, 0);
                    ac2B[t] = __builtin_amdgcn_mfma_f32_16x16x32_f16(A, B2b[s], ac2B[t], 0, 0, 0);
                }
            }
            // ---- layer 3: 64 -> 32 ----
            half8 B3a[2] = { repack2(ac2A[0], ac2A[2]), repack2(ac2A[1], ac2A[3]) };
            half8 B3b[2] = { repack2(ac2B[0], ac2B[2]), repack2(ac2B[1], ac2B[3]) };
            float4v ac3A[2], ac3B[2];
#pragma unroll
            for (int t = 0; t < 2; ++t) {
                ac3A[t] = b3v[m][t];
                ac3B[t] = b3v[m][t];
#pragma unroll
                for (int s = 0; s < 2; ++s) {
                    half8 A = *(const half8*)(mb + W3F + ((t * 2 + s) * 64 + lane) * 16);
                    ac3A[t] = __builtin_amdgcn_mfma_f32_16x16x32_f16(A, B3a[s], ac3A[t], 0, 0, 0);
                    ac3B[t] = __builtin_amdgcn_mfma_f32_16x16x32_f16(A, B3b[s], ac3B[t], 0, 0, 0);
                }
            }
            // ---- layer 4: 32 -> 1 ----
            float oA = 0.f, oB = 0.f;
#pragma unroll
            for (int r = 0; r < 4; ++r) {
                oA = fmaf(lrelu(ac3A[0][r]), w4v[m][0][r], oA);
                oB = fmaf(lrelu(ac3B[0][r]), w4v[m][0][r], oB);
            }
#pragma unroll
            for (int r = 0; r < 4; ++r) {
                oA = fmaf(lrelu(ac3A[1][r]), w4v[m][1][r], oA);
                oB = fmaf(lrelu(ac3B[1][r]), w4v[m][1][r], oB);
            }
            oA += __shfl_xor(oA, 16, 64); oA += __shfl_xor(oA, 32, 64);
            oB += __shfl_xor(oB, 16, 64); oB += __shfl_xor(oB, 32, 64);
            if (m == 0) { resA0 = oA; resB0 = oB; }
            else        { resA1 = oA; resB1 = oB; }
        }
        int ea = ta * 16 + n, eb = tb * 16 + n;
        if (q == 0) {
            if (ea < nE) { out[ea] = resA0 + b4s0; out[nE + ea] = resA1 + b4s1; }
            if (eb < nE) { out[eb] = resB0 + b4s0; out[nE + eb] = resB1 + b4s1; }
        }
#pragma unroll
        for (int s = 0; s < 4; ++s) { GA[s] = GAn[s]; GB[s] = GBn[s]; }
    }

    // consume warm registers (never-taken, data-dependent guard defeats DCE)
    junk ^= Wa0 ^ Wb0 ^ Wa1 ^ Wb1 ^ Wa2 ^ Wb2;
    if (nE < 0 && junk != 0)
        out[0] = -1.0f;
}

extern "C" void kernel_launch(void* const* d_in, const int* in_sizes, int n_in,
                              void* d_out, int out_size, void* d_ws, size_t ws_size,
                              hipStream_t stream)
{
    const float* x_src = (const float*)d_in[0];
    const float* x_dst = (const float*)d_in[1];
    const int*   eidx  = (const int*)d_in[2];
    const float* ew1 = (const float*)d_in[3];
    const float* eb1 = (const float*)d_in[4];
    const float* ww1 = (const float*)d_in[5];
    const float* wb1 = (const float*)d_in[6];
    const float* ew2 = (const float*)d_in[7];
    const float* eb2 = (const float*)d_in[8];
    const float* ww2 = (const float*)d_in[9];
    const float* wb2 = (const float*)d_in[10];
    const float* ew3 = (const float*)d_in[11];
    const float* eb3 = (const float*)d_in[12];
    const float* ww3 = (const float*)d_in[13];
    const float* wb3 = (const float*)d_in[14];
    const float* ew4 = (const float*)d_in[15];
    const float* eb4 = (const float*)d_in[16];
    const float* ww4 = (const float*)d_in[17];
    const float* wb4 = (const float*)d_in[18];
    float* out = (float*)d_out;

    const int nE = in_sizes[2] / 2;          // 2 x E index array (int32)
    const int nNodeElems = in_sizes[0];      // N_NODES * 64
    unsigned char* ws = (unsigned char*)d_ws;
    _Float16* xs16 = (_Float16*)(ws + WS_X16_OFF);
    _Float16* xd16 = xs16 + nNodeElems;

    prep_all<<<1024, 256, 0, stream>>>(ew1, eb1, ew2, eb2, ew3, eb3, ew4,
                                       ww1, wb1, ww2, wb2, ww3, wb3, ww4,
                                       x_src, x_dst, xs16, xd16, nNodeElems / 4, ws);

    const int nt32 = (nE + 31) / 32;
    edge_mlp_mfma<<<512, 256, 0, stream>>>(ws, xs16, xd16, eidx, eb4, wb4,
                                           out, nE, nt32);
}